// Round 3
// baseline (245.105 us; speedup 1.0000x reference)
//
#include <hip/hip_runtime.h>

// GlobalAttentionPooling: tensor_square_0e -> selu -> @W -> segment softmax -> weighted segment sum
// N nodes, 80 f32 ft (32 scalar + 16 x 3-vec), NG=1024 graphs (sorted batch_index), F=664.
//
// Math identities (validated rounds 1-4, absmax 3.9e-3):
//   selu const term cancels in softmax; pre-scale s by sqrt(log2e), v by sqrt(log2e/sqrt3)
//   so pair products are f*log2e -> exp2 directly. out_g = (sum nf*ex)/z_g.
//
// Round-8: I-cache theory. r5 (88us, VALUBusy 35%) and r7 (145us, VALUBusy 21.6%) have
//   IDENTICAL VALU-issue time (31us-equiv) -- r7 only added code bytes and only added stall.
//   Phase-1 fully unrolled = ~20-30KB straight-line code > 32KB L1I, zero reuse, all waves
//   thrash. Fix: ROLL the scalar triangle (272 f2-iters unchanged, no garbage):
//   per-thread scalar row lives in LDS (stride 33 -> (l+i)%32 banks, 2-way = free);
//   outer i rolled, inner q rolled with 1-iter explicit prefetch of s_q/W. Vector part
//   (72 iters ~4KB) stays unrolled. Total code ~6-8KB << L1I. Phase 2 verbatim from r5.

typedef float f2 __attribute__((ext_vector_type(2)));

#define C0 32
#define C1 16
#define NODE_F 80
#define NG_CONST 1024
#define NPB 320                 // nodes per block == threads per block (1 thread/node)
#define TPB 320

#define SELU_SCALE 1.0507009873554804934193349852946
#define SELU_ALPHA 1.6732632423543772848170429916717
#define LOG2E      1.4426950408889634073599246810019

#define CS_SCALE 1.2011224087864498f    // sqrt(log2e)
#define CV_SCALE 0.91271231102878545f   // sqrt(log2e/sqrt(3))

// ws float layout:
//   [0, 81920)        S accum: [1024 graphs][80 ch]
//   [81920, 82944)    z accum: [1024]
//   [82944, 84224)    Wpad: 512 f2 scalar-part rows (32x16) then 128 f2 vec-part rows (16x8)
#define WS_S 0
#define WS_Z 81920
#define WS_W 82944

__device__ __forceinline__ int ks_idx(int i, int j) { return i * C0 - (i * (i - 1)) / 2 + (j - i); }
__device__ __forceinline__ int kv_idx(int i, int j) { return 528 + i * C1 - (i * (i - 1)) / 2 + (j - i); }

// zero the accumulators + build padded W tables
__global__ __launch_bounds__(256) void prep_kernel(
    const float* __restrict__ W, float* __restrict__ ws)
{
    const int t = blockIdx.x * blockDim.x + threadIdx.x;
    if (t < 82944) {
        ws[t] = 0.0f;                       // S and z
    } else {
        int u = t - 82944;
        if (u < 512) {                      // Ws: i in [0,32), q in [0,16)
            int i = u >> 4, q = u & 15;
            int j0 = 2 * q, j1 = 2 * q + 1;
            ws[WS_W + 2 * u]     = (j0 >= i) ? W[ks_idx(i, j0)] : 0.0f;
            ws[WS_W + 2 * u + 1] = (j1 >= i) ? W[ks_idx(i, j1)] : 0.0f;
        } else if (u < 640) {               // Wv: i in [0,16), q in [0,8)
            int v = u - 512;
            int i = v >> 3, q = v & 7;
            int j0 = 2 * q, j1 = 2 * q + 1;
            ws[WS_W + 1024 + 2 * v]     = (j0 >= i) ? W[kv_idx(i, j0)] : 0.0f;
            ws[WS_W + 1024 + 2 * v + 1] = (j1 >= i) ? W[kv_idx(i, j1)] : 0.0f;
        }
    }
}

__global__ __launch_bounds__(TPB, 2) void main_kernel(
    const float* __restrict__ nf, const int* __restrict__ bi,
    const float* __restrict__ ws, float* __restrict__ S,
    float* __restrict__ z, int N)
{
    __shared__ __align__(16) float Wlds[1280];
    __shared__ float srow[NPB * 33 + 8];    // per-thread scalar row, stride 33 (+pad for prefetch overrun)
    __shared__ float exl[NPB];
    __shared__ int   bil[NPB];

    const int tid  = threadIdx.x;
    const int base = blockIdx.x * NPB;
    const float4* g4 = (const float4*)nf;

    #pragma unroll
    for (int u = tid; u < 1280; u += TPB) Wlds[u] = ws[WS_W + u];

    const int  n     = base + tid;
    const bool valid = (n < N);
    const int  nn    = valid ? n : (N - 1);
    bil[tid] = bi[nn];

    const float4* gp = g4 + (size_t)nn * 20;

    // scalar half -> scaled -> own LDS row (private, no cross-thread use)
    float* my = srow + tid * 33;
    #pragma unroll
    for (int q = 0; q < 8; ++q) {
        float4 r = gp[q];
        my[4 * q + 0] = r.x * CS_SCALE;
        my[4 * q + 1] = r.y * CS_SCALE;
        my[4 * q + 2] = r.z * CS_SCALE;
        my[4 * q + 3] = r.w * CS_SCALE;
    }
    // vector half -> registers (held across scalar loop; vmcnt drained at vp build)
    float4 rv[12];
    #pragma unroll
    for (int q = 0; q < 12; ++q) rv[q] = gp[8 + q];

    __syncthreads();                        // Wlds + bil ready

    // ---- phase 1a: scalar triangle, ROLLED (272 f2-iters, small code) ----
    f2 accA = (f2)0.f, accB = (f2)0.f;
    const f2* wbase = (const f2*)Wlds;      // 512 f2, rows of 16
    float si = my[0];

    #pragma unroll 1
    for (int i = 0; i < 32; ++i) {
        const float si_n = my[i + 1];       // prefetch next row's si (my[32] is pad)
        const f2* wrow = wbase + i * 16;
        const int qs = i >> 1;
        float a = my[2 * qs], b = my[2 * qs + 1];
        f2 w = wrow[qs];
        #pragma unroll 2
        for (int q = qs; q < 16; ++q) {
            const float a_n = my[2 * q + 2];    // 1-iter prefetch; overrun stays in pad/next row
            const float b_n = my[2 * q + 3];
            const f2    w_n = wrow[q + 1];      // overrun lands in Wv region, unused
            f2 f = f2{si * a, si * b};
            f2 p = __builtin_elementwise_max(f, (f2)0.f);
            f2 m = __builtin_elementwise_min(f, (f2)0.f);
            f2 e; e.x = __builtin_amdgcn_exp2f(m.x);
                  e.y = __builtin_amdgcn_exp2f(m.y);
            accA = __builtin_elementwise_fma(w, p, accA);
            accB = __builtin_elementwise_fma(w, e, accB);
            a = a_n; b = b_n; w = w_n;
        }
        si = si_n;
    }

    // ---- phase 1b: vector triangle, unrolled (72 f2-iters, ~4KB code) ----
    const float* rvf = (const float*)rv;
    f2 vp[8][3];
    #pragma unroll
    for (int q = 0; q < 8; ++q) {
        #pragma unroll
        for (int c3 = 0; c3 < 3; ++c3)
            vp[q][c3] = f2{rvf[6 * q + c3], rvf[6 * q + 3 + c3]} * CV_SCALE;
    }
    const f2* WvL = (const f2*)(Wlds + 1024); // 128 f2, rows of 8

    #pragma unroll
    for (int i = 0; i < C1; ++i) {
        const int k = i >> 1;
        const float vi0 = (i & 1) ? vp[k][0].y : vp[k][0].x;
        const float vi1 = (i & 1) ? vp[k][1].y : vp[k][1].x;
        const float vi2 = (i & 1) ? vp[k][2].y : vp[k][2].x;
        #pragma unroll
        for (int q = k; q < 8; ++q) {
            f2 f = vp[q][0] * f2{vi0, vi0};
            f = __builtin_elementwise_fma(vp[q][1], f2{vi1, vi1}, f);
            f = __builtin_elementwise_fma(vp[q][2], f2{vi2, vi2}, f);
            f2 p = __builtin_elementwise_max(f, (f2)0.f);
            f2 m = __builtin_elementwise_min(f, (f2)0.f);
            f2 e; e.x = __builtin_amdgcn_exp2f(m.x);
                  e.y = __builtin_amdgcn_exp2f(m.y);
            f2 w = WvL[i * 8 + q];
            accA = __builtin_elementwise_fma(w, p, accA);
            accB = __builtin_elementwise_fma(w, e, accB);
        }
    }

    const float A1 = accA.x + accA.y;
    const float A2 = accB.x + accB.y;
    const float l2 = fmaf((float)SELU_SCALE, A1,
                          (float)(SELU_SCALE * SELU_ALPHA * LOG2E) * A2);
    exl[tid] = valid ? __builtin_amdgcn_exp2f(l2) : 0.0f;
    __syncthreads();

    // ---- phase 2: thread (no, c4) sums 20 contiguous nodes' channel-group, flush per graph run ----
    const int no = tid / 20;       // 0..15
    const int c4 = tid % 20;
    int cg = bil[no * 20];
    float4 acc = make_float4(0.f, 0.f, 0.f, 0.f);
    float  zacc = 0.0f;

    #pragma unroll
    for (int k = 0; k < 20; ++k) {
        const int nl = no * 20 + k;
        const int g2 = bil[nl];
        if (g2 != cg) {
            unsafeAtomicAdd(&S[cg * NODE_F + c4 * 4 + 0], acc.x);
            unsafeAtomicAdd(&S[cg * NODE_F + c4 * 4 + 1], acc.y);
            unsafeAtomicAdd(&S[cg * NODE_F + c4 * 4 + 2], acc.z);
            unsafeAtomicAdd(&S[cg * NODE_F + c4 * 4 + 3], acc.w);
            if (c4 == 0) unsafeAtomicAdd(&z[cg], zacc);
            acc = make_float4(0.f, 0.f, 0.f, 0.f); zacc = 0.0f; cg = g2;
        }
        int idx = base + nl; if (idx > N - 1) idx = N - 1;   // pad nodes have w=0
        const float  w = exl[nl];
        const float4 v = g4[(size_t)idx * 20 + c4];
        acc.x = fmaf(v.x, w, acc.x); acc.y = fmaf(v.y, w, acc.y);
        acc.z = fmaf(v.z, w, acc.z); acc.w = fmaf(v.w, w, acc.w);
        zacc += w;
    }
    unsafeAtomicAdd(&S[cg * NODE_F + c4 * 4 + 0], acc.x);
    unsafeAtomicAdd(&S[cg * NODE_F + c4 * 4 + 1], acc.y);
    unsafeAtomicAdd(&S[cg * NODE_F + c4 * 4 + 2], acc.z);
    unsafeAtomicAdd(&S[cg * NODE_F + c4 * 4 + 3], acc.w);
    if (c4 == 0) unsafeAtomicAdd(&z[cg], zacc);
}

__global__ __launch_bounds__(256) void divide_kernel(
    const float* __restrict__ S, const float* __restrict__ z,
    float* __restrict__ out)
{
    const int t = blockIdx.x * blockDim.x + threadIdx.x;
    if (t >= NG_CONST * NODE_F) return;
    const float zz = z[t / NODE_F];
    out[t] = (zz > 0.0f) ? (S[t] / zz) : 0.0f;
}

extern "C" void kernel_launch(void* const* d_in, const int* in_sizes, int n_in,
                              void* d_out, int out_size, void* d_ws, size_t ws_size,
                              hipStream_t stream) {
    const float* nf = (const float*)d_in[0];   // (N, 80) f32
    const int*   bi = (const int*)d_in[1];     // (N,) i32 sorted
    // d_in[2] = num_graphs (static 1024)
    const float* W  = (const float*)d_in[3];   // (664,) f32
    float* out = (float*)d_out;

    const int N = in_sizes[0] / NODE_F;
    float* ws = (float*)d_ws;
    float* S  = ws + WS_S;
    float* z  = ws + WS_Z;

    hipLaunchKernelGGL(prep_kernel, dim3(332), dim3(256), 0, stream, W, ws);
    hipLaunchKernelGGL(main_kernel, dim3((N + NPB - 1) / NPB), dim3(TPB), 0, stream,
                       nf, bi, ws, S, z, N);
    hipLaunchKernelGGL(divide_kernel, dim3((NG_CONST * NODE_F + 255) / 256), dim3(256),
                       0, stream, S, z, out);
}

// Round 4
// 244.618 us; speedup vs baseline: 1.0020x; 1.0020x over previous
//
#include <hip/hip_runtime.h>

// GlobalAttentionPooling: tensor_square_0e -> selu -> @W -> segment softmax -> weighted segment sum
// N nodes, 80 f32 ft (32 scalar + 16 x 3-vec), NG=1024 graphs (sorted batch_index), F=664.
//
// Math identities (validated rounds 1-4, absmax 3.9e-3):
//   selu const term cancels in softmax; pre-scale s by sqrt(log2e), v by sqrt(log2e/sqrt3)
//   so pair products are f*log2e -> exp2 directly. out_g = (sum nf*ex)/z_g.
//
// Round-9: I$ theory test. Ledger: VALU-issue time constant ~31-37us across r5/r7/r8 while
//   wall varies 88-148; r5 4.6 waves/SIMD x 23% duty = 105% issue demand yet VALU=35% ->
//   stalls CORRELATED across waves -> L1I thrash of ~30KB zero-reuse unrolled code.
//   Fix: scalar triangle = rolled outer i / STATIC inner q (fixed ranges via W zero-padding:
//   i<16 -> q=0..15, i>=16 -> q=8..15; garbage pairs hit w=0). s2[16] in REGISTERS (static
//   idx only); only dynamic value is si=my[i], 1 LDS read/row prefetched 1 row ahead (r8's
//   mistake was per-ITERATION my[] reads). W as 8x ds_read_b128/row. +33% f2-iters, but
//   body ~1.6KB, total ~12KB << 32KB L1I. Vector part + phase 2 verbatim r5.
//   Falsifier: VALUBusy <=40% at main ~90-110us kills the I$ theory.

typedef float f2 __attribute__((ext_vector_type(2)));

#define C0 32
#define C1 16
#define NODE_F 80
#define NG_CONST 1024
#define NPB 320                 // nodes per block == threads per block (1 thread/node)
#define TPB 320

#define SELU_SCALE 1.0507009873554804934193349852946
#define SELU_ALPHA 1.6732632423543772848170429916717
#define LOG2E      1.4426950408889634073599246810019

#define CS_SCALE 1.2011224087864498f    // sqrt(log2e)
#define CV_SCALE 0.91271231102878545f   // sqrt(log2e/sqrt(3))

// ws float layout:
//   [0, 81920)        S accum: [1024 graphs][80 ch]
//   [81920, 82944)    z accum: [1024]
//   [82944, 84224)    Wpad: 512 f2 scalar-part rows (32x16) then 128 f2 vec-part rows (16x8)
#define WS_S 0
#define WS_Z 81920
#define WS_W 82944

__device__ __forceinline__ int ks_idx(int i, int j) { return i * C0 - (i * (i - 1)) / 2 + (j - i); }
__device__ __forceinline__ int kv_idx(int i, int j) { return 528 + i * C1 - (i * (i - 1)) / 2 + (j - i); }

// zero the accumulators + build padded W tables
__global__ __launch_bounds__(256) void prep_kernel(
    const float* __restrict__ W, float* __restrict__ ws)
{
    const int t = blockIdx.x * blockDim.x + threadIdx.x;
    if (t < 82944) {
        ws[t] = 0.0f;                       // S and z
    } else {
        int u = t - 82944;
        if (u < 512) {                      // Ws: i in [0,32), q in [0,16)
            int i = u >> 4, q = u & 15;
            int j0 = 2 * q, j1 = 2 * q + 1;
            ws[WS_W + 2 * u]     = (j0 >= i) ? W[ks_idx(i, j0)] : 0.0f;
            ws[WS_W + 2 * u + 1] = (j1 >= i) ? W[ks_idx(i, j1)] : 0.0f;
        } else if (u < 640) {               // Wv: i in [0,16), q in [0,8)
            int v = u - 512;
            int i = v >> 3, q = v & 7;
            int j0 = 2 * q, j1 = 2 * q + 1;
            ws[WS_W + 1024 + 2 * v]     = (j0 >= i) ? W[kv_idx(i, j0)] : 0.0f;
            ws[WS_W + 1024 + 2 * v + 1] = (j1 >= i) ? W[kv_idx(i, j1)] : 0.0f;
        }
    }
}

__global__ __launch_bounds__(TPB, 2) void main_kernel(
    const float* __restrict__ nf, const int* __restrict__ bi,
    const float* __restrict__ ws, float* __restrict__ S,
    float* __restrict__ z, int N)
{
    __shared__ __align__(16) float Wlds[1280];
    __shared__ float srow[NPB * 33 + 8];    // per-thread scalar row (si lookups), stride 33: 2-way banks, free
    __shared__ float exl[NPB];
    __shared__ int   bil[NPB];

    const int tid  = threadIdx.x;
    const int base = blockIdx.x * NPB;
    const float4* g4 = (const float4*)nf;

    #pragma unroll
    for (int u = tid; u < 1280; u += TPB) Wlds[u] = ws[WS_W + u];

    const int  n     = base + tid;
    const bool valid = (n < N);
    const int  nn    = valid ? n : (N - 1);
    bil[tid] = bi[nn];

    const float4* gp = g4 + (size_t)nn * 20;

    // scalar half: scaled into REGISTERS (s2, static-indexed) + private LDS row (si, dynamic-indexed)
    float* my = srow + tid * 33;
    f2 s2[16];
    #pragma unroll
    for (int q = 0; q < 8; ++q) {
        float4 r = gp[q];
        f2 lo = f2{r.x, r.y} * CS_SCALE;
        f2 hi = f2{r.z, r.w} * CS_SCALE;
        s2[2 * q]     = lo;
        s2[2 * q + 1] = hi;
        my[4 * q + 0] = lo.x; my[4 * q + 1] = lo.y;
        my[4 * q + 2] = hi.x; my[4 * q + 3] = hi.y;
    }
    __syncthreads();                        // Wlds + bil (+ own srow) ready

    f2 accA[2], accB[2];
    accA[0] = (f2)0.f; accA[1] = (f2)0.f; accB[0] = (f2)0.f; accB[1] = (f2)0.f;
    const float4* w4 = (const float4*)Wlds;   // 8 float4 per scalar row

    float si = my[0];
    // ---- range A: rows 0..15, static q=0..15 (w=0 pads kill q<i/2 garbage) ----
    #pragma unroll 1
    for (int i = 0; i < 16; ++i) {
        const float si_n = my[i + 1];       // prefetch next row's si (16-iter distance)
        const float4* wrow = w4 + i * 8;
        const f2 si2 = f2{si, si};
        #pragma unroll
        for (int q2 = 0; q2 < 8; ++q2) {
            const float4 wq = wrow[q2];     // ds_read_b128, static offset
            const f2 w0 = f2{wq.x, wq.y};
            const f2 w1 = f2{wq.z, wq.w};
            f2 f0 = si2 * s2[2 * q2];
            f2 f1 = si2 * s2[2 * q2 + 1];
            f2 p0 = __builtin_elementwise_max(f0, (f2)0.f);
            f2 p1 = __builtin_elementwise_max(f1, (f2)0.f);
            f2 m0 = __builtin_elementwise_min(f0, (f2)0.f);
            f2 m1 = __builtin_elementwise_min(f1, (f2)0.f);
            f2 e0, e1;
            e0.x = __builtin_amdgcn_exp2f(m0.x); e0.y = __builtin_amdgcn_exp2f(m0.y);
            e1.x = __builtin_amdgcn_exp2f(m1.x); e1.y = __builtin_amdgcn_exp2f(m1.y);
            accA[0] = __builtin_elementwise_fma(w0, p0, accA[0]);
            accB[0] = __builtin_elementwise_fma(w0, e0, accB[0]);
            accA[1] = __builtin_elementwise_fma(w1, p1, accA[1]);
            accB[1] = __builtin_elementwise_fma(w1, e1, accB[1]);
        }
        si = si_n;
    }

    // issue vector-half global loads now; range B covers their latency
    float4 rv[12];
    #pragma unroll
    for (int q = 0; q < 12; ++q) rv[q] = gp[8 + q];

    // ---- range B: rows 16..31, static q=8..15 ----
    #pragma unroll 1
    for (int i = 16; i < 32; ++i) {
        const float si_n = my[i + 1];       // my[32] is pad (value unused after last row)
        const float4* wrow = w4 + i * 8;
        const f2 si2 = f2{si, si};
        #pragma unroll
        for (int q2 = 4; q2 < 8; ++q2) {
            const float4 wq = wrow[q2];
            const f2 w0 = f2{wq.x, wq.y};
            const f2 w1 = f2{wq.z, wq.w};
            f2 f0 = si2 * s2[2 * q2];
            f2 f1 = si2 * s2[2 * q2 + 1];
            f2 p0 = __builtin_elementwise_max(f0, (f2)0.f);
            f2 p1 = __builtin_elementwise_max(f1, (f2)0.f);
            f2 m0 = __builtin_elementwise_min(f0, (f2)0.f);
            f2 m1 = __builtin_elementwise_min(f1, (f2)0.f);
            f2 e0, e1;
            e0.x = __builtin_amdgcn_exp2f(m0.x); e0.y = __builtin_amdgcn_exp2f(m0.y);
            e1.x = __builtin_amdgcn_exp2f(m1.x); e1.y = __builtin_amdgcn_exp2f(m1.y);
            accA[0] = __builtin_elementwise_fma(w0, p0, accA[0]);
            accB[0] = __builtin_elementwise_fma(w0, e0, accB[0]);
            accA[1] = __builtin_elementwise_fma(w1, p1, accA[1]);
            accB[1] = __builtin_elementwise_fma(w1, e1, accB[1]);
        }
        si = si_n;
    }

    // ---- vector triangle: unrolled, verbatim r5 (72 f2-iters) ----
    const float* rvf = (const float*)rv;
    f2 vp[8][3];
    #pragma unroll
    for (int q = 0; q < 8; ++q) {
        #pragma unroll
        for (int c3 = 0; c3 < 3; ++c3)
            vp[q][c3] = f2{rvf[6 * q + c3], rvf[6 * q + 3 + c3]} * CV_SCALE;
    }
    const f2* WvL = (const f2*)(Wlds + 1024); // 128 f2, rows of 8

    #pragma unroll
    for (int i = 0; i < C1; ++i) {
        const int k = i >> 1;
        const float vi0 = (i & 1) ? vp[k][0].y : vp[k][0].x;
        const float vi1 = (i & 1) ? vp[k][1].y : vp[k][1].x;
        const float vi2 = (i & 1) ? vp[k][2].y : vp[k][2].x;
        #pragma unroll
        for (int q = k; q < 8; ++q) {
            f2 f = vp[q][0] * f2{vi0, vi0};
            f = __builtin_elementwise_fma(vp[q][1], f2{vi1, vi1}, f);
            f = __builtin_elementwise_fma(vp[q][2], f2{vi2, vi2}, f);
            f2 p = __builtin_elementwise_max(f, (f2)0.f);
            f2 m = __builtin_elementwise_min(f, (f2)0.f);
            f2 e; e.x = __builtin_amdgcn_exp2f(m.x);
                  e.y = __builtin_amdgcn_exp2f(m.y);
            f2 w = WvL[i * 8 + q];
            accA[q & 1] = __builtin_elementwise_fma(w, p, accA[q & 1]);
            accB[q & 1] = __builtin_elementwise_fma(w, e, accB[q & 1]);
        }
    }

    const float A1 = (accA[0].x + accA[0].y) + (accA[1].x + accA[1].y);
    const float A2 = (accB[0].x + accB[0].y) + (accB[1].x + accB[1].y);
    const float l2 = fmaf((float)SELU_SCALE, A1,
                          (float)(SELU_SCALE * SELU_ALPHA * LOG2E) * A2);
    exl[tid] = valid ? __builtin_amdgcn_exp2f(l2) : 0.0f;
    __syncthreads();

    // ---- phase 2: thread (no, c4) sums 20 contiguous nodes' channel-group, flush per graph run ----
    const int no = tid / 20;       // 0..15
    const int c4 = tid % 20;
    int cg = bil[no * 20];
    float4 acc = make_float4(0.f, 0.f, 0.f, 0.f);
    float  zacc = 0.0f;

    #pragma unroll
    for (int k = 0; k < 20; ++k) {
        const int nl = no * 20 + k;
        const int g2 = bil[nl];
        if (g2 != cg) {
            unsafeAtomicAdd(&S[cg * NODE_F + c4 * 4 + 0], acc.x);
            unsafeAtomicAdd(&S[cg * NODE_F + c4 * 4 + 1], acc.y);
            unsafeAtomicAdd(&S[cg * NODE_F + c4 * 4 + 2], acc.z);
            unsafeAtomicAdd(&S[cg * NODE_F + c4 * 4 + 3], acc.w);
            if (c4 == 0) unsafeAtomicAdd(&z[cg], zacc);
            acc = make_float4(0.f, 0.f, 0.f, 0.f); zacc = 0.0f; cg = g2;
        }
        int idx = base + nl; if (idx > N - 1) idx = N - 1;   // pad nodes have w=0
        const float  w = exl[nl];
        const float4 v = g4[(size_t)idx * 20 + c4];
        acc.x = fmaf(v.x, w, acc.x); acc.y = fmaf(v.y, w, acc.y);
        acc.z = fmaf(v.z, w, acc.z); acc.w = fmaf(v.w, w, acc.w);
        zacc += w;
    }
    unsafeAtomicAdd(&S[cg * NODE_F + c4 * 4 + 0], acc.x);
    unsafeAtomicAdd(&S[cg * NODE_F + c4 * 4 + 1], acc.y);
    unsafeAtomicAdd(&S[cg * NODE_F + c4 * 4 + 2], acc.z);
    unsafeAtomicAdd(&S[cg * NODE_F + c4 * 4 + 3], acc.w);
    if (c4 == 0) unsafeAtomicAdd(&z[cg], zacc);
}

__global__ __launch_bounds__(256) void divide_kernel(
    const float* __restrict__ S, const float* __restrict__ z,
    float* __restrict__ out)
{
    const int t = blockIdx.x * blockDim.x + threadIdx.x;
    if (t >= NG_CONST * NODE_F) return;
    const float zz = z[t / NODE_F];
    out[t] = (zz > 0.0f) ? (S[t] / zz) : 0.0f;
}

extern "C" void kernel_launch(void* const* d_in, const int* in_sizes, int n_in,
                              void* d_out, int out_size, void* d_ws, size_t ws_size,
                              hipStream_t stream) {
    const float* nf = (const float*)d_in[0];   // (N, 80) f32
    const int*   bi = (const int*)d_in[1];     // (N,) i32 sorted
    // d_in[2] = num_graphs (static 1024)
    const float* W  = (const float*)d_in[3];   // (664,) f32
    float* out = (float*)d_out;

    const int N = in_sizes[0] / NODE_F;
    float* ws = (float*)d_ws;
    float* S  = ws + WS_S;
    float* z  = ws + WS_Z;

    hipLaunchKernelGGL(prep_kernel, dim3(332), dim3(256), 0, stream, W, ws);
    hipLaunchKernelGGL(main_kernel, dim3((N + NPB - 1) / NPB), dim3(TPB), 0, stream,
                       nf, bi, ws, S, z, N);
    hipLaunchKernelGGL(divide_kernel, dim3((NG_CONST * NODE_F + 255) / 256), dim3(256),
                       0, stream, S, z, out);
}

// Round 5
// 210.766 us; speedup vs baseline: 1.1629x; 1.1606x over previous
//
#include <hip/hip_runtime.h>

// GlobalAttentionPooling: tensor_square_0e -> selu -> @W -> segment softmax -> weighted segment sum
// N nodes, 80 f32 ft (32 scalar + 16 x 3-vec), NG=1024 graphs (sorted batch_index), F=664.
//
// Math identities (validated rounds 1-4, absmax 3.9e-3):
//   selu const term cancels in softmax; pre-scale s by sqrt(log2e), v by sqrt(log2e/sqrt3)
//   so pair products are f*log2e -> exp2 directly. out_g = (sum nf*ex)/z_g.
//
// Round-10: TRANS-PIPE theory. Ledger: VALUBusy x dur == VALU work (31us r5, 33.6 r6, 42 r9
//   = 1.33x work) in every round; wall invariant at ~88us main for constant exp-count under
//   radically different structures; occupancy/wave changes don't move it -> shared-resource
//   saturation. Fit: 688 v_exp/wave x 4688 waves x ~64cyc / 1024 SIMD / 2.4GHz = 87.4us ==
//   measured 88.3. v_exp_f32 on gfx950 is unmeasured in refs; hypothesis: far below quarter
//   rate. Single-variable experiment: r5 kernel VERBATIM, only exp2 -> packed-FMA polynomial
//   (2^m = 2^rint(m) * deg-5 Taylor on r in [-.5,.5], rel err 3e-6; scale via (i+127)<<23).
//   Falsifier: main ~88 & VALUBusy ~35% -> theory dead, next probe = phase1/2 split kernels.

typedef float f2 __attribute__((ext_vector_type(2)));

#define C0 32
#define C1 16
#define NODE_F 80
#define NG_CONST 1024
#define NPB 320                 // nodes per block == threads per block (1 thread/node)
#define TPB 320

#define SELU_SCALE 1.0507009873554804934193349852946
#define SELU_ALPHA 1.6732632423543772848170429916717
#define LOG2E      1.4426950408889634073599246810019

#define CS_SCALE 1.2011224087864498f    // sqrt(log2e)
#define CV_SCALE 0.91271231102878545f   // sqrt(log2e/sqrt(3))

// ws float layout:
//   [0, 81920)        S accum: [1024 graphs][80 ch]
//   [81920, 82944)    z accum: [1024]
//   [82944, 84224)    Wpad: 512 f2 scalar-part rows (32x16) then 128 f2 vec-part rows (16x8)
#define WS_S 0
#define WS_Z 81920
#define WS_W 82944

__device__ __forceinline__ int ks_idx(int i, int j) { return i * C0 - (i * (i - 1)) / 2 + (j - i); }
__device__ __forceinline__ int kv_idx(int i, int j) { return 528 + i * C1 - (i * (i - 1)) / 2 + (j - i); }

// 2^m for m <= 0, no transcendental: 2^rint(m) * poly(m - rint(m)).
// Taylor deg-5 of 2^r on [-0.5,0.5]: next term ln2^6/720 * 0.5^6 ~ 2.4e-6 rel.
__device__ __forceinline__ f2 exp2_poly(f2 m) {
    m = __builtin_elementwise_max(m, (f2)(-126.0f));
    f2 n; n.x = __builtin_rintf(m.x); n.y = __builtin_rintf(m.y);   // v_rndne_f32
    f2 r = m - n;
    const f2 k5 = (f2)0.0013333558146f;
    const f2 k4 = (f2)0.0096181291076f;
    const f2 k3 = (f2)0.0555041086648f;
    const f2 k2 = (f2)0.2402265069591f;
    const f2 k1 = (f2)0.6931471805599f;
    f2 p = __builtin_elementwise_fma(k5, r, k4);
    p = __builtin_elementwise_fma(p, r, k3);
    p = __builtin_elementwise_fma(p, r, k2);
    p = __builtin_elementwise_fma(p, r, k1);
    p = __builtin_elementwise_fma(p, r, (f2)1.0f);
    const int ix = (int)n.x, iy = (int)n.y;
    f2 s;
    s.x = __int_as_float((ix + 127) << 23);
    s.y = __int_as_float((iy + 127) << 23);
    return p * s;
}

// zero the accumulators + build padded W tables
__global__ __launch_bounds__(256) void prep_kernel(
    const float* __restrict__ W, float* __restrict__ ws)
{
    const int t = blockIdx.x * blockDim.x + threadIdx.x;
    if (t < 82944) {
        ws[t] = 0.0f;                       // S and z
    } else {
        int u = t - 82944;
        if (u < 512) {                      // Ws: i in [0,32), q in [0,16)
            int i = u >> 4, q = u & 15;
            int j0 = 2 * q, j1 = 2 * q + 1;
            ws[WS_W + 2 * u]     = (j0 >= i) ? W[ks_idx(i, j0)] : 0.0f;
            ws[WS_W + 2 * u + 1] = (j1 >= i) ? W[ks_idx(i, j1)] : 0.0f;
        } else if (u < 640) {               // Wv: i in [0,16), q in [0,8)
            int v = u - 512;
            int i = v >> 3, q = v & 7;
            int j0 = 2 * q, j1 = 2 * q + 1;
            ws[WS_W + 1024 + 2 * v]     = (j0 >= i) ? W[kv_idx(i, j0)] : 0.0f;
            ws[WS_W + 1024 + 2 * v + 1] = (j1 >= i) ? W[kv_idx(i, j1)] : 0.0f;
        }
    }
}

__global__ __launch_bounds__(TPB, 2) void main_kernel(
    const float* __restrict__ nf, const int* __restrict__ bi,
    const float* __restrict__ ws, float* __restrict__ S,
    float* __restrict__ z, int N)
{
    __shared__ __align__(16) float Wlds[1280];
    __shared__ float exl[NPB];
    __shared__ int   bil[NPB];

    const int tid  = threadIdx.x;
    const int base = blockIdx.x * NPB;
    const float4* g4 = (const float4*)nf;

    #pragma unroll
    for (int u = tid; u < 1280; u += TPB) Wlds[u] = ws[WS_W + u];

    const int  n     = base + tid;
    const bool valid = (n < N);
    const int  nn    = valid ? n : (N - 1);
    bil[tid] = bi[nn];
    __syncthreads();                        // Wlds ready

    // ---- phase 1: per-thread row (registers), fully unrolled triangle, DS-only W ----
    float4 row4[20];
    #pragma unroll
    for (int q = 0; q < 20; ++q) row4[q] = g4[(size_t)nn * 20 + q];
    const float* row = (const float*)row4;

    const f2* WsL = (const f2*)Wlds;          // 512 f2
    const f2* WvL = (const f2*)(Wlds + 1024); // 128 f2

    f2 accA[2], accB[2];
    accA[0] = (f2)0.f; accA[1] = (f2)0.f; accB[0] = (f2)0.f; accB[1] = (f2)0.f;

    {   // scalar part: 528 triu pairs as j-pair f2 (272 f2-iters)
        f2 s2[C0 / 2];
        #pragma unroll
        for (int q = 0; q < C0 / 2; ++q)
            s2[q] = f2{row[2 * q], row[2 * q + 1]} * CS_SCALE;
        #pragma unroll
        for (int i = 0; i < C0; ++i) {
            const float si = (i & 1) ? s2[i >> 1].y : s2[i >> 1].x;
            const f2 si2 = f2{si, si};
            #pragma unroll
            for (int q = i >> 1; q < C0 / 2; ++q) {
                f2 f = si2 * s2[q];
                f2 p = __builtin_elementwise_max(f, (f2)0.f);
                f2 m = __builtin_elementwise_min(f, (f2)0.f);
                f2 e = exp2_poly(m);
                f2 w = WsL[i * 16 + q];             // broadcast ds_read_b64, pad slots = 0
                accA[q & 1] = __builtin_elementwise_fma(w, p, accA[q & 1]);
                accB[q & 1] = __builtin_elementwise_fma(w, e, accB[q & 1]);
            }
        }
    }
    {   // vector part: 136 triu dot pairs as j-pair f2 (72 f2-iters)
        f2 vp[C1 / 2][3];
        #pragma unroll
        for (int q = 0; q < C1 / 2; ++q) {
            #pragma unroll
            for (int c = 0; c < 3; ++c)
                vp[q][c] = f2{row[C0 + 6 * q + c], row[C0 + 6 * q + 3 + c]} * CV_SCALE;
        }
        #pragma unroll
        for (int i = 0; i < C1; ++i) {
            const int iq = i >> 1;
            const float vi0 = (i & 1) ? vp[iq][0].y : vp[iq][0].x;
            const float vi1 = (i & 1) ? vp[iq][1].y : vp[iq][1].x;
            const float vi2 = (i & 1) ? vp[iq][2].y : vp[iq][2].x;
            #pragma unroll
            for (int q = i >> 1; q < C1 / 2; ++q) {
                f2 f = vp[q][0] * f2{vi0, vi0};
                f = __builtin_elementwise_fma(vp[q][1], f2{vi1, vi1}, f);
                f = __builtin_elementwise_fma(vp[q][2], f2{vi2, vi2}, f);
                f2 p = __builtin_elementwise_max(f, (f2)0.f);
                f2 m = __builtin_elementwise_min(f, (f2)0.f);
                f2 e = exp2_poly(m);
                f2 w = WvL[i * 8 + q];
                accA[q & 1] = __builtin_elementwise_fma(w, p, accA[q & 1]);
                accB[q & 1] = __builtin_elementwise_fma(w, e, accB[q & 1]);
            }
        }
    }

    const float A1 = accA[0].x + accA[0].y + accA[1].x + accA[1].y;
    const float A2 = accB[0].x + accB[0].y + accB[1].x + accB[1].y;
    const float l2 = fmaf((float)SELU_SCALE, A1,
                          (float)(SELU_SCALE * SELU_ALPHA * LOG2E) * A2);
    exl[tid] = valid ? __builtin_amdgcn_exp2f(l2) : 0.0f;
    __syncthreads();

    // ---- phase 2: thread (no, c4) sums 20 contiguous nodes' channel-group, flush per graph run ----
    const int no = tid / 20;       // 0..15
    const int c4 = tid % 20;
    int cg = bil[no * 20];
    float4 acc = make_float4(0.f, 0.f, 0.f, 0.f);
    float  zacc = 0.0f;

    #pragma unroll
    for (int k = 0; k < 20; ++k) {
        const int nl = no * 20 + k;
        const int g2 = bil[nl];
        if (g2 != cg) {
            unsafeAtomicAdd(&S[cg * NODE_F + c4 * 4 + 0], acc.x);
            unsafeAtomicAdd(&S[cg * NODE_F + c4 * 4 + 1], acc.y);
            unsafeAtomicAdd(&S[cg * NODE_F + c4 * 4 + 2], acc.z);
            unsafeAtomicAdd(&S[cg * NODE_F + c4 * 4 + 3], acc.w);
            if (c4 == 0) unsafeAtomicAdd(&z[cg], zacc);
            acc = make_float4(0.f, 0.f, 0.f, 0.f); zacc = 0.0f; cg = g2;
        }
        int idx = base + nl; if (idx > N - 1) idx = N - 1;   // pad nodes have w=0
        const float  w = exl[nl];
        const float4 v = g4[(size_t)idx * 20 + c4];
        acc.x = fmaf(v.x, w, acc.x); acc.y = fmaf(v.y, w, acc.y);
        acc.z = fmaf(v.z, w, acc.z); acc.w = fmaf(v.w, w, acc.w);
        zacc += w;
    }
    unsafeAtomicAdd(&S[cg * NODE_F + c4 * 4 + 0], acc.x);
    unsafeAtomicAdd(&S[cg * NODE_F + c4 * 4 + 1], acc.y);
    unsafeAtomicAdd(&S[cg * NODE_F + c4 * 4 + 2], acc.z);
    unsafeAtomicAdd(&S[cg * NODE_F + c4 * 4 + 3], acc.w);
    if (c4 == 0) unsafeAtomicAdd(&z[cg], zacc);
}

__global__ __launch_bounds__(256) void divide_kernel(
    const float* __restrict__ S, const float* __restrict__ z,
    float* __restrict__ out)
{
    const int t = blockIdx.x * blockDim.x + threadIdx.x;
    if (t >= NG_CONST * NODE_F) return;
    const float zz = z[t / NODE_F];
    out[t] = (zz > 0.0f) ? (S[t] / zz) : 0.0f;
}

extern "C" void kernel_launch(void* const* d_in, const int* in_sizes, int n_in,
                              void* d_out, int out_size, void* d_ws, size_t ws_size,
                              hipStream_t stream) {
    const float* nf = (const float*)d_in[0];   // (N, 80) f32
    const int*   bi = (const int*)d_in[1];     // (N,) i32 sorted
    // d_in[2] = num_graphs (static 1024)
    const float* W  = (const float*)d_in[3];   // (664,) f32
    float* out = (float*)d_out;

    const int N = in_sizes[0] / NODE_F;
    float* ws = (float*)d_ws;
    float* S  = ws + WS_S;
    float* z  = ws + WS_Z;

    hipLaunchKernelGGL(prep_kernel, dim3(332), dim3(256), 0, stream, W, ws);
    hipLaunchKernelGGL(main_kernel, dim3((N + NPB - 1) / NPB), dim3(TPB), 0, stream,
                       nf, bi, ws, S, z, N);
    hipLaunchKernelGGL(divide_kernel, dim3((NG_CONST * NODE_F + 255) / 256), dim3(256),
                       0, stream, S, z, out);
}